// Round 7
// baseline (5122.682 us; speedup 1.0000x reference)
//
#include <hip/hip_runtime.h>
#include <math.h>

#define N_NODES 50000
#define N_EDGES 1600000
#define D_IN 128
#define D_HID 128
#define D_OUT 64
#define N_EXPERT 16
#define NB 8     // nodes per block in last kernel
#define GNB 64   // nodes per chunk in expert GEMM
#define NYB 256  // chunk-slots per expert (stride loop handles any skew)
#define NBG 16   // nodes per block in gate kernel (50000 % 16 == 0)
#define NGBLK (N_NODES / NBG)   // 3125 gate blocks per layer
#define XR4 33   // padded x-chunk row stride in float4 (132 floats)

// ---------------- gate: logits + softmax-std + argmax ------------------------
// One block = 256 threads = NBG(16) nodes. Thread (e = t&15, j = t>>4).
// Wg staged TRANSPOSED in LDS (wgt[e][d], +4 pad); x staged via float4.
__global__ __launch_bounds__(256) void gate_kernel(
    const float* __restrict__ x, const float* __restrict__ Wg, const float* __restrict__ bg,
    int* __restrict__ eidx, float* __restrict__ gpart)
{
    __shared__ float xs[NBG][132];           // +4 pad: bank rotation per row
    __shared__ float wgt[N_EXPERT][132];     // transposed gate weights, +4 pad
    __shared__ float sred[NBG];
    const int n0 = blockIdx.x * NBG;
    const int t = threadIdx.x;

    // Wg: 512 float4 coalesced reads -> transposed scalar LDS stores (2/thread)
    {
        const float4* __restrict__ Wg4 = (const float4*)Wg;
        float4 v = Wg4[t];
        int d = t >> 2, e4 = (t & 3) * 4;
        wgt[e4 + 0][d] = v.x; wgt[e4 + 1][d] = v.y; wgt[e4 + 2][d] = v.z; wgt[e4 + 3][d] = v.w;
        v = Wg4[t + 256];
        d += 64;
        wgt[e4 + 0][d] = v.x; wgt[e4 + 1][d] = v.y; wgt[e4 + 2][d] = v.z; wgt[e4 + 3][d] = v.w;
    }
    // x: 16 rows * 32 float4 = 512 float4 (2/thread), coalesced
    {
        int id = t, row = id >> 5, c4 = id & 31;
        *(float4*)&xs[row][4 * c4] = ((const float4*)(x + (size_t)(n0 + row) * 128))[c4];
        id = t + 256; row = id >> 5; c4 = id & 31;
        *(float4*)&xs[row][4 * c4] = ((const float4*)(x + (size_t)(n0 + row) * 128))[c4];
    }
    __syncthreads();

    const int e = t & 15, j = t >> 4;
    float lg = bg[e];
    #pragma unroll
    for (int d4 = 0; d4 < 32; ++d4) {        // d-ascending FMA order preserved
        const float4 xv = *(const float4*)&xs[j][4 * d4];
        const float4 wv = *(const float4*)&wgt[e][4 * d4];
        lg = fmaf(xv.x, wv.x, lg);
        lg = fmaf(xv.y, wv.y, lg);
        lg = fmaf(xv.z, wv.z, lg);
        lg = fmaf(xv.w, wv.w, lg);
    }

    // 16-lane-group reductions (lanes of one node are contiguous)
    float mx = lg;
    #pragma unroll
    for (int m = 8; m >= 1; m >>= 1) mx = fmaxf(mx, __shfl_xor(mx, m, 16));
    const float ex = expf(lg - mx);
    float se = ex;
    #pragma unroll
    for (int m = 8; m >= 1; m >>= 1) se += __shfl_xor(se, m, 16);
    const float p = ex / se;
    const float dm = p - (1.f / 16.f);
    float var = dm * dm;
    #pragma unroll
    for (int m = 8; m >= 1; m >>= 1) var += __shfl_xor(var, m, 16);

    // argmax over logits (== argmax over softmax), first-index on ties
    float bv = lg; int bi = e;
    #pragma unroll
    for (int m = 8; m >= 1; m >>= 1) {
        const float ov = __shfl_xor(bv, m, 16);
        const int oi = __shfl_xor(bi, m, 16);
        if (ov > bv || (ov == bv && oi < bi)) { bv = ov; bi = oi; }
    }
    if (e == 0) {
        eidx[n0 + j] = bi;
        sred[j] = sqrtf(var * (1.f / 15.f));
    }
    __syncthreads();
    if (t == 0) {
        float s = 0.f;
        #pragma unroll
        for (int jj = 0; jj < NBG; ++jj) s += sred[jj];
        gpart[blockIdx.x] = s;
    }
}

// ---------------- expert bucketing: hist16 -> scan16 -> scatter16 ------------
__global__ __launch_bounds__(256) void hist16_kernel(
    const int* __restrict__ eidx, int* __restrict__ ecnt)
{
    __shared__ int lcnt[N_EXPERT];
    const int t = threadIdx.x;
    const int n = blockIdx.x * 256 + t;
    if (t < N_EXPERT) lcnt[t] = 0;
    __syncthreads();
    if (n < N_NODES) atomicAdd(&lcnt[eidx[n]], 1);
    __syncthreads();
    if (t < N_EXPERT && lcnt[t] > 0) atomicAdd(&ecnt[t], lcnt[t]);
}

__global__ void scan16_kernel(const int* __restrict__ ecnt,
                              int* __restrict__ eoff, int* __restrict__ ecur)
{
    if (threadIdx.x == 0) {
        int s = 0;
        #pragma unroll
        for (int e = 0; e < N_EXPERT; ++e) { eoff[e] = s; ecur[e] = s; s += ecnt[e]; }
        eoff[N_EXPERT] = s;
    }
}

__global__ __launch_bounds__(256) void scatter16_kernel(
    const int* __restrict__ eidx, int* __restrict__ ecur, int* __restrict__ elist)
{
    __shared__ int lcnt[N_EXPERT];
    __shared__ int lbase[N_EXPERT];
    const int t = threadIdx.x;
    const int n = blockIdx.x * 256 + t;
    if (t < N_EXPERT) lcnt[t] = 0;
    __syncthreads();
    int e = 0, lpos = 0;
    if (n < N_NODES) { e = eidx[n]; lpos = atomicAdd(&lcnt[e], 1); }
    __syncthreads();
    if (t < N_EXPERT && lcnt[t] > 0) lbase[t] = atomicAdd(&ecur[t], lcnt[t]);
    __syncthreads();
    if (n < N_NODES) elist[lbase[e] + lpos] = n;
}

// ---------------- per-expert GEMM: y[n] = x[n] @ We[e] + be[e] ---------------
// grid = (16 experts, NYB=256 chunk-slots) with a chunk-stride loop (handles
// arbitrary skew; layer-2 gating collapses onto few experts).
// Thread tile: dg = t&31 -> dims 4dg..4dg+3, ng = t>>5 -> nodes 8ng..8ng+7.
// W streams from L1/L2 as FULLY-COALESCED float4 wave-loads (512 B/row) with
// explicit wA/wB double-buffer prefetch; x chunk in LDS padded to 132 floats
// per row (bank rotation -> no 4-way conflict). d-ascending FMA order kept.
__global__ __launch_bounds__(256) void expert_gemm_kernel(
    const float* __restrict__ x, const float* __restrict__ We, const float* __restrict__ be,
    const int* __restrict__ eoff, const int* __restrict__ elist, float* __restrict__ y)
{
    __shared__ float xsd[GNB * 132];  // 33 KB, padded
    const int e = blockIdx.x;
    const int t = threadIdx.x;
    const int row0 = eoff[e];
    const int row1 = eoff[e + 1];

    const int dg = t & 31;   // dims 4*dg .. 4*dg+3
    const int ng = t >> 5;   // nodes 8*ng .. 8*ng+7
    const float4* __restrict__ Wv = (const float4*)(We + (size_t)e * 16384);
    const float4* __restrict__ Xv = (const float4*)xsd;
    const float4 bv = *(const float4*)&be[e * 128 + 4 * dg];

    for (int chunk = blockIdx.y;; chunk += (int)gridDim.y) {
        const int start = row0 + chunk * GNB;
        if (start >= row1) break;   // block-uniform

        // stage 64 node rows of x (float4, coalesced; dummy = first node)
        #pragma unroll
        for (int i = 0; i < 8; ++i) {
            const int id = t + 256 * i;
            const int n = id >> 5;
            const int d4 = id & 31;
            const int idx = start + n;
            const int node = elist[idx < row1 ? idx : start];
            ((float4*)xsd)[n * XR4 + d4] = ((const float4*)(x + (size_t)node * 128))[d4];
        }
        __syncthreads();

        float4 acc[8];
        #pragma unroll
        for (int k = 0; k < 8; ++k) acc[k] = bv;  // bias-init (baseline order)

        float4 wA[4], wB[4];
        #pragma unroll
        for (int r = 0; r < 4; ++r) wA[r] = Wv[r * 32 + dg];   // rows 0..3

        #pragma unroll
        for (int d4 = 0; d4 < 32; d4 += 2) {
            // prefetch rows for d4+1 while computing d4
            #pragma unroll
            for (int r = 0; r < 4; ++r) wB[r] = Wv[(4 * (d4 + 1) + r) * 32 + dg];
            #pragma unroll
            for (int k = 0; k < 8; ++k) {
                const float4 xv = Xv[(8 * ng + k) * XR4 + d4];
                acc[k].x = fmaf(xv.x, wA[0].x, acc[k].x);
                acc[k].y = fmaf(xv.x, wA[0].y, acc[k].y);
                acc[k].z = fmaf(xv.x, wA[0].z, acc[k].z);
                acc[k].w = fmaf(xv.x, wA[0].w, acc[k].w);
                acc[k].x = fmaf(xv.y, wA[1].x, acc[k].x);
                acc[k].y = fmaf(xv.y, wA[1].y, acc[k].y);
                acc[k].z = fmaf(xv.y, wA[1].z, acc[k].z);
                acc[k].w = fmaf(xv.y, wA[1].w, acc[k].w);
                acc[k].x = fmaf(xv.z, wA[2].x, acc[k].x);
                acc[k].y = fmaf(xv.z, wA[2].y, acc[k].y);
                acc[k].z = fmaf(xv.z, wA[2].z, acc[k].z);
                acc[k].w = fmaf(xv.z, wA[2].w, acc[k].w);
                acc[k].x = fmaf(xv.w, wA[3].x, acc[k].x);
                acc[k].y = fmaf(xv.w, wA[3].y, acc[k].y);
                acc[k].z = fmaf(xv.w, wA[3].z, acc[k].z);
                acc[k].w = fmaf(xv.w, wA[3].w, acc[k].w);
            }
            // prefetch rows for d4+2 while computing d4+1
            if (d4 + 2 < 32) {
                #pragma unroll
                for (int r = 0; r < 4; ++r) wA[r] = Wv[(4 * (d4 + 2) + r) * 32 + dg];
            }
            #pragma unroll
            for (int k = 0; k < 8; ++k) {
                const float4 xv = Xv[(8 * ng + k) * XR4 + d4 + 1];
                acc[k].x = fmaf(xv.x, wB[0].x, acc[k].x);
                acc[k].y = fmaf(xv.x, wB[0].y, acc[k].y);
                acc[k].z = fmaf(xv.x, wB[0].z, acc[k].z);
                acc[k].w = fmaf(xv.x, wB[0].w, acc[k].w);
                acc[k].x = fmaf(xv.y, wB[1].x, acc[k].x);
                acc[k].y = fmaf(xv.y, wB[1].y, acc[k].y);
                acc[k].z = fmaf(xv.y, wB[1].z, acc[k].z);
                acc[k].w = fmaf(xv.y, wB[1].w, acc[k].w);
                acc[k].x = fmaf(xv.z, wB[2].x, acc[k].x);
                acc[k].y = fmaf(xv.z, wB[2].y, acc[k].y);
                acc[k].z = fmaf(xv.z, wB[2].z, acc[k].z);
                acc[k].w = fmaf(xv.z, wB[2].w, acc[k].w);
                acc[k].x = fmaf(xv.w, wB[3].x, acc[k].x);
                acc[k].y = fmaf(xv.w, wB[3].y, acc[k].y);
                acc[k].z = fmaf(xv.w, wB[3].z, acc[k].z);
                acc[k].w = fmaf(xv.w, wB[3].w, acc[k].w);
            }
        }

        #pragma unroll
        for (int k = 0; k < 8; ++k) {
            const int idx = start + 8 * ng + k;
            if (idx < row1)
                *(float4*)&y[(size_t)elist[idx] * 128 + 4 * dg] = acc[k];
        }

        __syncthreads();   // xsd fully consumed before next-chunk restage
    }
}

// ---------------- final plain linear 128 -> 64, 8 nodes/block ----------------
__global__ __launch_bounds__(64) void last_kernel(
    const float* __restrict__ h, const float* __restrict__ W, float* __restrict__ y)
{
    __shared__ float xs[NB][128];
    const int n0 = blockIdx.x * NB, t = threadIdx.x;
    #pragma unroll
    for (int j = 0; j < NB; ++j) {
        xs[j][t] = h[(size_t)(n0 + j) * 128 + t];
        xs[j][t + 64] = h[(size_t)(n0 + j) * 128 + t + 64];
    }
    __syncthreads();
    float a0 = 0.f, a1 = 0.f, a2 = 0.f, a3 = 0.f;
    float a4 = 0.f, a5 = 0.f, a6 = 0.f, a7 = 0.f;
    #pragma unroll 4
    for (int d = 0; d < 128; ++d) {
        const float w = W[d * 64 + t];
        a0 = fmaf(xs[0][d], w, a0);
        a1 = fmaf(xs[1][d], w, a1);
        a2 = fmaf(xs[2][d], w, a2);
        a3 = fmaf(xs[3][d], w, a3);
        a4 = fmaf(xs[4][d], w, a4);
        a5 = fmaf(xs[5][d], w, a5);
        a6 = fmaf(xs[6][d], w, a6);
        a7 = fmaf(xs[7][d], w, a7);
    }
    y[(size_t)(n0 + 0) * 64 + t] = a0;
    y[(size_t)(n0 + 1) * 64 + t] = a1;
    y[(size_t)(n0 + 2) * 64 + t] = a2;
    y[(size_t)(n0 + 3) * 64 + t] = a3;
    y[(size_t)(n0 + 4) * 64 + t] = a4;
    y[(size_t)(n0 + 5) * 64 + t] = a5;
    y[(size_t)(n0 + 6) * 64 + t] = a6;
    y[(size_t)(n0 + 7) * 64 + t] = a7;
}

// ---------------- CSR build: histogram -> scan -> fill -----------------------
__global__ void hist_kernel(const int* __restrict__ edst, int* __restrict__ cnt)
{
    const int i = blockIdx.x * blockDim.x + threadIdx.x;
    if (i < N_EDGES) atomicAdd(&cnt[edst[i]], 1);
}

// Single-block scan, hoisted: per-thread serial sum (49 entries) -> one
// 1024-wide Hillis-Steele -> serial write-back. cursor is a SEPARATE buffer.
__global__ __launch_bounds__(1024) void scan_kernel(
    const int* __restrict__ cnt, int* __restrict__ rowptr, int* __restrict__ cursor)
{
    __shared__ int buf[1024];
    const int t = threadIdx.x;
    const int base = t * 49;               // 49*1024 = 50176 >= N_NODES
    int s = 0;
    for (int i = 0; i < 49; ++i) {
        const int idx = base + i;
        if (idx < N_NODES) s += cnt[idx];
    }
    buf[t] = s;
    __syncthreads();
    for (int off = 1; off < 1024; off <<= 1) {
        const int add = (t >= off) ? buf[t - off] : 0;
        __syncthreads();
        buf[t] += add;
        __syncthreads();
    }
    int run = buf[t] - s;                  // exclusive prefix of this chunk
    for (int i = 0; i < 49; ++i) {
        const int idx = base + i;
        if (idx < N_NODES) {
            const int c = cnt[idx];
            rowptr[idx] = run; cursor[idx] = run;
            run += c;
        }
    }
    if (t == 1023) rowptr[N_NODES] = run;  // total edges
}

__global__ void fill_kernel(const int* __restrict__ esrc, const int* __restrict__ edst,
                            int* __restrict__ cursor, int* __restrict__ csr_src)
{
    const int i = blockIdx.x * blockDim.x + threadIdx.x;
    if (i < N_EDGES) {
        const int p = atomicAdd(&cursor[edst[i]], 1);
        csr_src[p] = esrc[i];
    }
}

// ---------------- gather aggregation: out[n] = bias + sum_{e in row n} h[src] -
template <int D, bool RELU>
__global__ __launch_bounds__(D) void gather_kernel(
    const float* __restrict__ h, const int* __restrict__ rowptr,
    const int* __restrict__ csr_src, const float* __restrict__ bias,
    float* __restrict__ out)
{
    const int n = blockIdx.x, t = threadIdx.x;
    const int s0 = rowptr[n], s1 = rowptr[n + 1];
    float a0 = bias[t], a1 = 0.f, a2 = 0.f, a3 = 0.f;
    int e = s0;
    for (; e + 3 < s1; e += 4) {
        const int i0 = csr_src[e + 0];
        const int i1 = csr_src[e + 1];
        const int i2 = csr_src[e + 2];
        const int i3 = csr_src[e + 3];
        a0 += h[(size_t)i0 * D + t];
        a1 += h[(size_t)i1 * D + t];
        a2 += h[(size_t)i2 * D + t];
        a3 += h[(size_t)i3 * D + t];
    }
    for (; e < s1; ++e) a0 += h[(size_t)csr_src[e] * D + t];
    float acc = (a0 + a1) + (a2 + a3);
    if (RELU) acc = fmaxf(acc, 0.f);
    out[(size_t)n * D + t] = acc;
}

// ---------------- finalize: reduce 2*NGBLK gate partials + write tail --------
__global__ __launch_bounds__(1024) void finalize_kernel(
    const float* __restrict__ gpart, float* __restrict__ out_tail)
{
    __shared__ float wsum[16];
    const int t = threadIdx.x;
    float s = 0.f;
    for (int i = t; i < 2 * NGBLK; i += 1024) s += gpart[i];
    #pragma unroll
    for (int m = 32; m >= 1; m >>= 1) s += __shfl_xor(s, m, 64);
    if ((t & 63) == 0) wsum[t >> 6] = s;
    __syncthreads();
    if (t == 0) {
        float tot = 0.f;
        #pragma unroll
        for (int w = 0; w < 16; ++w) tot += wsum[w];
        out_tail[0] = tot * (0.5f / (float)N_NODES);
        out_tail[1] = 1.0f;
    }
}

extern "C" void kernel_launch(void* const* d_in, const int* in_sizes, int n_in,
                              void* d_out, int out_size, void* d_ws, size_t ws_size,
                              hipStream_t stream)
{
    const float* x     = (const float*)d_in[0];
    const int*   edge  = (const int*)d_in[1];
    const float* Wg1   = (const float*)d_in[2];
    const float* bg1   = (const float*)d_in[3];
    const float* We1   = (const float*)d_in[4];
    const float* be1   = (const float*)d_in[5];
    const float* b1    = (const float*)d_in[6];
    const float* Wg2   = (const float*)d_in[7];
    const float* bg2   = (const float*)d_in[8];
    const float* We2   = (const float*)d_in[9];
    const float* be2   = (const float*)d_in[10];
    const float* b2    = (const float*)d_in[11];
    const float* Wlast = (const float*)d_in[12];
    const float* blast = (const float*)d_in[13];
    float* out = (float*)d_out;

    const int* esrc = edge;
    const int* edst = edge + N_EDGES;

    char* ws = (char*)d_ws;
    size_t off = 0;
    float* gpart = (float*)(ws + off); off += (size_t)2 * NGBLK * 4 + 252; off &= ~(size_t)255;
    float* A = (float*)(ws + off); off += (size_t)N_NODES * 128 * 4;
    float* B = (float*)(ws + off); off += (size_t)N_NODES * 128 * 4;
    int* rowptr = (int*)(ws + off); off += (size_t)(N_NODES + 1) * 4 + 252; off &= ~(size_t)255;
    int* cnt = (int*)(ws + off); off += (size_t)N_NODES * 4 + 252; off &= ~(size_t)255;
    int* cursor = (int*)(ws + off); off += (size_t)N_NODES * 4 + 252; off &= ~(size_t)255;
    int* csr_src = (int*)(ws + off); off += (size_t)N_EDGES * 4;
    int* elist = (int*)(ws + off); off += (size_t)N_NODES * 4 + 252; off &= ~(size_t)255;
    int* meta = (int*)(ws + off); off += 256;
    int* ecnt = meta;          // 16
    int* eoff = meta + 16;     // 17
    int* ecur = meta + 33;     // 16
    int* eidx = cnt;           // cnt is free after scan_kernel

    // ---- CSR build ----
    hipMemsetAsync(cnt, 0, (size_t)N_NODES * 4, stream);
    hist_kernel<<<(N_EDGES + 255) / 256, 256, 0, stream>>>(edst, cnt);
    scan_kernel<<<1, 1024, 0, stream>>>(cnt, rowptr, cursor);
    fill_kernel<<<(N_EDGES + 255) / 256, 256, 0, stream>>>(esrc, edst, cursor, csr_src);

    const int nbk = (N_NODES + 255) / 256;

    // ---- layer 1 ----
    gate_kernel<<<NGBLK, 256, 0, stream>>>(x, Wg1, bg1, eidx, gpart);
    hipMemsetAsync(ecnt, 0, 64, stream);
    hist16_kernel<<<nbk, 256, 0, stream>>>(eidx, ecnt);
    scan16_kernel<<<1, 64, 0, stream>>>(ecnt, eoff, ecur);
    scatter16_kernel<<<nbk, 256, 0, stream>>>(eidx, ecur, elist);
    expert_gemm_kernel<<<dim3(N_EXPERT, NYB), 256, 0, stream>>>(x, We1, be1, eoff, elist, A);
    gather_kernel<128, true><<<N_NODES, 128, 0, stream>>>(A, rowptr, csr_src, b1, B);

    // ---- layer 2 ----
    gate_kernel<<<NGBLK, 256, 0, stream>>>(B, Wg2, bg2, eidx, gpart + NGBLK);
    hipMemsetAsync(ecnt, 0, 64, stream);
    hist16_kernel<<<nbk, 256, 0, stream>>>(eidx, ecnt);
    scan16_kernel<<<1, 64, 0, stream>>>(ecnt, eoff, ecur);
    scatter16_kernel<<<nbk, 256, 0, stream>>>(eidx, ecur, elist);
    expert_gemm_kernel<<<dim3(N_EXPERT, NYB), 256, 0, stream>>>(B, We2, be2, eoff, elist, A);
    gather_kernel<128, true><<<N_NODES, 128, 0, stream>>>(A, rowptr, csr_src, b2, B);

    // ---- layer 3 (plain GCNConv) ----
    last_kernel<<<N_NODES / NB, 64, 0, stream>>>(B, Wlast, A);
    gather_kernel<64, false><<<N_NODES, 64, 0, stream>>>(A, rowptr, csr_src, blast, out);

    finalize_kernel<<<1, 1024, 0, stream>>>(gpart, out + (size_t)N_NODES * 64);
}

// Round 8
// 778.411 us; speedup vs baseline: 6.5809x; 6.5809x over previous
//
#include <hip/hip_runtime.h>
#include <math.h>

#define N_NODES 50000
#define N_EDGES 1600000
#define D_IN 128
#define D_HID 128
#define D_OUT 64
#define N_EXPERT 16
#define NB 8     // nodes per block in last kernel
#define GNB 128  // nodes per chunk in expert GEMM (W traffic amortized 2x)
#define NYB 256  // chunk-slots per expert (stride loop handles any skew)
#define NBG 16   // nodes per block in gate kernel (50000 % 16 == 0)
#define NGBLK (N_NODES / NBG)   // 3125 gate blocks per layer
#define XR4 33   // padded x-chunk row stride in float4 (132 floats)

// ---------------- gate: logits + softmax-std + argmax ------------------------
// One block = 256 threads = NBG(16) nodes. Thread (e = t&15, j = t>>4).
// Wg staged TRANSPOSED in LDS (wgt[e][d], +4 pad); x staged via float4.
__global__ __launch_bounds__(256) void gate_kernel(
    const float* __restrict__ x, const float* __restrict__ Wg, const float* __restrict__ bg,
    int* __restrict__ eidx, float* __restrict__ gpart)
{
    __shared__ float xs[NBG][132];           // +4 pad: bank rotation per row
    __shared__ float wgt[N_EXPERT][132];     // transposed gate weights, +4 pad
    __shared__ float sred[NBG];
    const int n0 = blockIdx.x * NBG;
    const int t = threadIdx.x;

    // Wg: 512 float4 coalesced reads -> transposed scalar LDS stores (2/thread)
    {
        const float4* __restrict__ Wg4 = (const float4*)Wg;
        float4 v = Wg4[t];
        int d = t >> 2, e4 = (t & 3) * 4;
        wgt[e4 + 0][d] = v.x; wgt[e4 + 1][d] = v.y; wgt[e4 + 2][d] = v.z; wgt[e4 + 3][d] = v.w;
        v = Wg4[t + 256];
        d += 64;
        wgt[e4 + 0][d] = v.x; wgt[e4 + 1][d] = v.y; wgt[e4 + 2][d] = v.z; wgt[e4 + 3][d] = v.w;
    }
    // x: 16 rows * 32 float4 = 512 float4 (2/thread), coalesced
    {
        int id = t, row = id >> 5, c4 = id & 31;
        *(float4*)&xs[row][4 * c4] = ((const float4*)(x + (size_t)(n0 + row) * 128))[c4];
        id = t + 256; row = id >> 5; c4 = id & 31;
        *(float4*)&xs[row][4 * c4] = ((const float4*)(x + (size_t)(n0 + row) * 128))[c4];
    }
    __syncthreads();

    const int e = t & 15, j = t >> 4;
    float lg = bg[e];
    #pragma unroll
    for (int d4 = 0; d4 < 32; ++d4) {        // d-ascending FMA order preserved
        const float4 xv = *(const float4*)&xs[j][4 * d4];
        const float4 wv = *(const float4*)&wgt[e][4 * d4];
        lg = fmaf(xv.x, wv.x, lg);
        lg = fmaf(xv.y, wv.y, lg);
        lg = fmaf(xv.z, wv.z, lg);
        lg = fmaf(xv.w, wv.w, lg);
    }

    // 16-lane-group reductions (lanes of one node are contiguous)
    float mx = lg;
    #pragma unroll
    for (int m = 8; m >= 1; m >>= 1) mx = fmaxf(mx, __shfl_xor(mx, m, 16));
    const float ex = expf(lg - mx);
    float se = ex;
    #pragma unroll
    for (int m = 8; m >= 1; m >>= 1) se += __shfl_xor(se, m, 16);
    const float p = ex / se;
    const float dm = p - (1.f / 16.f);
    float var = dm * dm;
    #pragma unroll
    for (int m = 8; m >= 1; m >>= 1) var += __shfl_xor(var, m, 16);

    // argmax over logits (== argmax over softmax), first-index on ties
    float bv = lg; int bi = e;
    #pragma unroll
    for (int m = 8; m >= 1; m >>= 1) {
        const float ov = __shfl_xor(bv, m, 16);
        const int oi = __shfl_xor(bi, m, 16);
        if (ov > bv || (ov == bv && oi < bi)) { bv = ov; bi = oi; }
    }
    if (e == 0) {
        eidx[n0 + j] = bi;
        sred[j] = sqrtf(var * (1.f / 15.f));
    }
    __syncthreads();
    if (t == 0) {
        float s = 0.f;
        #pragma unroll
        for (int jj = 0; jj < NBG; ++jj) s += sred[jj];
        gpart[blockIdx.x] = s;
    }
}

// ---------------- expert bucketing: hist16 -> scan16 -> scatter16 ------------
__global__ __launch_bounds__(256) void hist16_kernel(
    const int* __restrict__ eidx, int* __restrict__ ecnt)
{
    __shared__ int lcnt[N_EXPERT];
    const int t = threadIdx.x;
    const int n = blockIdx.x * 256 + t;
    if (t < N_EXPERT) lcnt[t] = 0;
    __syncthreads();
    if (n < N_NODES) atomicAdd(&lcnt[eidx[n]], 1);
    __syncthreads();
    if (t < N_EXPERT && lcnt[t] > 0) atomicAdd(&ecnt[t], lcnt[t]);
}

__global__ void scan16_kernel(const int* __restrict__ ecnt,
                              int* __restrict__ eoff, int* __restrict__ ecur)
{
    if (threadIdx.x == 0) {
        int s = 0;
        #pragma unroll
        for (int e = 0; e < N_EXPERT; ++e) { eoff[e] = s; ecur[e] = s; s += ecnt[e]; }
        eoff[N_EXPERT] = s;
    }
}

__global__ __launch_bounds__(256) void scatter16_kernel(
    const int* __restrict__ eidx, int* __restrict__ ecur, int* __restrict__ elist)
{
    __shared__ int lcnt[N_EXPERT];
    __shared__ int lbase[N_EXPERT];
    const int t = threadIdx.x;
    const int n = blockIdx.x * 256 + t;
    if (t < N_EXPERT) lcnt[t] = 0;
    __syncthreads();
    int e = 0, lpos = 0;
    if (n < N_NODES) { e = eidx[n]; lpos = atomicAdd(&lcnt[e], 1); }
    __syncthreads();
    if (t < N_EXPERT && lcnt[t] > 0) lbase[t] = atomicAdd(&ecur[t], lcnt[t]);
    __syncthreads();
    if (n < N_NODES) elist[lbase[e] + lpos] = n;
}

// ---------------- per-expert GEMM: y[n] = x[n] @ We[e] + be[e] ---------------
// grid = (16 experts, NYB=256 chunk-slots) + chunk-stride loop (handles the
// layer-2 gating collapse onto few experts).
// GNB=128 nodes/chunk: every wave still streams the full 64 KB We[e] once per
// chunk through L1/L2, but it now serves 2x nodes (W-restream was R6's bound).
// Thread tile: dg = t&31 -> dims 4dg..4dg+3, ng = t>>5 -> nodes 16ng..16ng+15.
// x chunk in LDS padded to 132 floats/row (bank rotation, no 4-way conflict).
// #pragma unroll 2 ONLY (R7 lesson: full unroll -> 256 VGPR + scratch spill).
__global__ __launch_bounds__(256, 2) void expert_gemm_kernel(
    const float* __restrict__ x, const float* __restrict__ We, const float* __restrict__ be,
    const int* __restrict__ eoff, const int* __restrict__ elist, float* __restrict__ y)
{
    __shared__ float xsd[GNB * 132];  // 66 KB padded -> 2 blocks/CU
    const int e = blockIdx.x;
    const int t = threadIdx.x;
    const int row0 = eoff[e];
    const int row1 = eoff[e + 1];

    const int dg = t & 31;   // dims 4*dg .. 4*dg+3
    const int ng = t >> 5;   // nodes 16*ng .. 16*ng+15
    const float4* __restrict__ Wv = (const float4*)(We + (size_t)e * 16384);
    const float4* __restrict__ Xv = (const float4*)xsd;
    const float4 bv = *(const float4*)&be[e * 128 + 4 * dg];

    for (int chunk = blockIdx.y;; chunk += (int)gridDim.y) {
        const int start = row0 + chunk * GNB;
        if (start >= row1) break;   // block-uniform

        // stage 128 node rows of x (float4, coalesced; dummy = first node)
        #pragma unroll
        for (int i = 0; i < 16; ++i) {
            const int id = t + 256 * i;
            const int n = id >> 5;
            const int d4 = id & 31;
            const int idx = start + n;
            const int node = elist[idx < row1 ? idx : start];
            ((float4*)xsd)[n * XR4 + d4] = ((const float4*)(x + (size_t)node * 128))[d4];
        }
        __syncthreads();

        float4 acc[16];
        #pragma unroll
        for (int k = 0; k < 16; ++k) acc[k] = bv;  // bias-init (baseline order)

        #pragma unroll 2
        for (int d4 = 0; d4 < 32; ++d4) {
            float4 w[4];   // W rows 4d4..4d4+3, this thread's 4 dims
            #pragma unroll
            for (int r = 0; r < 4; ++r) w[r] = Wv[(4 * d4 + r) * 32 + dg];
            #pragma unroll
            for (int k = 0; k < 16; ++k) {
                const float4 xv = Xv[(16 * ng + k) * XR4 + d4];
                acc[k].x = fmaf(xv.x, w[0].x, acc[k].x);
                acc[k].y = fmaf(xv.x, w[0].y, acc[k].y);
                acc[k].z = fmaf(xv.x, w[0].z, acc[k].z);
                acc[k].w = fmaf(xv.x, w[0].w, acc[k].w);
                acc[k].x = fmaf(xv.y, w[1].x, acc[k].x);
                acc[k].y = fmaf(xv.y, w[1].y, acc[k].y);
                acc[k].z = fmaf(xv.y, w[1].z, acc[k].z);
                acc[k].w = fmaf(xv.y, w[1].w, acc[k].w);
                acc[k].x = fmaf(xv.z, w[2].x, acc[k].x);
                acc[k].y = fmaf(xv.z, w[2].y, acc[k].y);
                acc[k].z = fmaf(xv.z, w[2].z, acc[k].z);
                acc[k].w = fmaf(xv.z, w[2].w, acc[k].w);
                acc[k].x = fmaf(xv.w, w[3].x, acc[k].x);
                acc[k].y = fmaf(xv.w, w[3].y, acc[k].y);
                acc[k].z = fmaf(xv.w, w[3].z, acc[k].z);
                acc[k].w = fmaf(xv.w, w[3].w, acc[k].w);
            }
        }

        #pragma unroll
        for (int k = 0; k < 16; ++k) {
            const int idx = start + 16 * ng + k;
            if (idx < row1)
                *(float4*)&y[(size_t)elist[idx] * 128 + 4 * dg] = acc[k];
        }

        __syncthreads();   // xsd fully consumed before next-chunk restage
    }
}

// ---------------- final plain linear 128 -> 64, 8 nodes/block ----------------
__global__ __launch_bounds__(64) void last_kernel(
    const float* __restrict__ h, const float* __restrict__ W, float* __restrict__ y)
{
    __shared__ float xs[NB][128];
    const int n0 = blockIdx.x * NB, t = threadIdx.x;
    #pragma unroll
    for (int j = 0; j < NB; ++j) {
        xs[j][t] = h[(size_t)(n0 + j) * 128 + t];
        xs[j][t + 64] = h[(size_t)(n0 + j) * 128 + t + 64];
    }
    __syncthreads();
    float a0 = 0.f, a1 = 0.f, a2 = 0.f, a3 = 0.f;
    float a4 = 0.f, a5 = 0.f, a6 = 0.f, a7 = 0.f;
    #pragma unroll 4
    for (int d = 0; d < 128; ++d) {
        const float w = W[d * 64 + t];
        a0 = fmaf(xs[0][d], w, a0);
        a1 = fmaf(xs[1][d], w, a1);
        a2 = fmaf(xs[2][d], w, a2);
        a3 = fmaf(xs[3][d], w, a3);
        a4 = fmaf(xs[4][d], w, a4);
        a5 = fmaf(xs[5][d], w, a5);
        a6 = fmaf(xs[6][d], w, a6);
        a7 = fmaf(xs[7][d], w, a7);
    }
    y[(size_t)(n0 + 0) * 64 + t] = a0;
    y[(size_t)(n0 + 1) * 64 + t] = a1;
    y[(size_t)(n0 + 2) * 64 + t] = a2;
    y[(size_t)(n0 + 3) * 64 + t] = a3;
    y[(size_t)(n0 + 4) * 64 + t] = a4;
    y[(size_t)(n0 + 5) * 64 + t] = a5;
    y[(size_t)(n0 + 6) * 64 + t] = a6;
    y[(size_t)(n0 + 7) * 64 + t] = a7;
}

// ---------------- CSR build: histogram -> scan -> fill -----------------------
__global__ void hist_kernel(const int* __restrict__ edst, int* __restrict__ cnt)
{
    const int i = blockIdx.x * blockDim.x + threadIdx.x;
    if (i < N_EDGES) atomicAdd(&cnt[edst[i]], 1);
}

// Single-block scan, hoisted: per-thread serial sum (49 entries) -> one
// 1024-wide Hillis-Steele -> serial write-back. cursor is a SEPARATE buffer.
__global__ __launch_bounds__(1024) void scan_kernel(
    const int* __restrict__ cnt, int* __restrict__ rowptr, int* __restrict__ cursor)
{
    __shared__ int buf[1024];
    const int t = threadIdx.x;
    const int base = t * 49;               // 49*1024 = 50176 >= N_NODES
    int s = 0;
    for (int i = 0; i < 49; ++i) {
        const int idx = base + i;
        if (idx < N_NODES) s += cnt[idx];
    }
    buf[t] = s;
    __syncthreads();
    for (int off = 1; off < 1024; off <<= 1) {
        const int add = (t >= off) ? buf[t - off] : 0;
        __syncthreads();
        buf[t] += add;
        __syncthreads();
    }
    int run = buf[t] - s;                  // exclusive prefix of this chunk
    for (int i = 0; i < 49; ++i) {
        const int idx = base + i;
        if (idx < N_NODES) {
            const int c = cnt[idx];
            rowptr[idx] = run; cursor[idx] = run;
            run += c;
        }
    }
    if (t == 1023) rowptr[N_NODES] = run;  // total edges
}

__global__ void fill_kernel(const int* __restrict__ esrc, const int* __restrict__ edst,
                            int* __restrict__ cursor, int* __restrict__ csr_src)
{
    const int i = blockIdx.x * blockDim.x + threadIdx.x;
    if (i < N_EDGES) {
        const int p = atomicAdd(&cursor[edst[i]], 1);
        csr_src[p] = esrc[i];
    }
}

// ---------------- gather aggregation: out[n] = bias + sum_{e in row n} h[src] -
template <int D, bool RELU>
__global__ __launch_bounds__(D) void gather_kernel(
    const float* __restrict__ h, const int* __restrict__ rowptr,
    const int* __restrict__ csr_src, const float* __restrict__ bias,
    float* __restrict__ out)
{
    const int n = blockIdx.x, t = threadIdx.x;
    const int s0 = rowptr[n], s1 = rowptr[n + 1];
    float a0 = bias[t], a1 = 0.f, a2 = 0.f, a3 = 0.f;
    int e = s0;
    for (; e + 3 < s1; e += 4) {
        const int i0 = csr_src[e + 0];
        const int i1 = csr_src[e + 1];
        const int i2 = csr_src[e + 2];
        const int i3 = csr_src[e + 3];
        a0 += h[(size_t)i0 * D + t];
        a1 += h[(size_t)i1 * D + t];
        a2 += h[(size_t)i2 * D + t];
        a3 += h[(size_t)i3 * D + t];
    }
    for (; e < s1; ++e) a0 += h[(size_t)csr_src[e] * D + t];
    float acc = (a0 + a1) + (a2 + a3);
    if (RELU) acc = fmaxf(acc, 0.f);
    out[(size_t)n * D + t] = acc;
}

// ---------------- finalize: reduce 2*NGBLK gate partials + write tail --------
__global__ __launch_bounds__(1024) void finalize_kernel(
    const float* __restrict__ gpart, float* __restrict__ out_tail)
{
    __shared__ float wsum[16];
    const int t = threadIdx.x;
    float s = 0.f;
    for (int i = t; i < 2 * NGBLK; i += 1024) s += gpart[i];
    #pragma unroll
    for (int m = 32; m >= 1; m >>= 1) s += __shfl_xor(s, m, 64);
    if ((t & 63) == 0) wsum[t >> 6] = s;
    __syncthreads();
    if (t == 0) {
        float tot = 0.f;
        #pragma unroll
        for (int w = 0; w < 16; ++w) tot += wsum[w];
        out_tail[0] = tot * (0.5f / (float)N_NODES);
        out_tail[1] = 1.0f;
    }
}

extern "C" void kernel_launch(void* const* d_in, const int* in_sizes, int n_in,
                              void* d_out, int out_size, void* d_ws, size_t ws_size,
                              hipStream_t stream)
{
    const float* x     = (const float*)d_in[0];
    const int*   edge  = (const int*)d_in[1];
    const float* Wg1   = (const float*)d_in[2];
    const float* bg1   = (const float*)d_in[3];
    const float* We1   = (const float*)d_in[4];
    const float* be1   = (const float*)d_in[5];
    const float* b1    = (const float*)d_in[6];
    const float* Wg2   = (const float*)d_in[7];
    const float* bg2   = (const float*)d_in[8];
    const float* We2   = (const float*)d_in[9];
    const float* be2   = (const float*)d_in[10];
    const float* b2    = (const float*)d_in[11];
    const float* Wlast = (const float*)d_in[12];
    const float* blast = (const float*)d_in[13];
    float* out = (float*)d_out;

    const int* esrc = edge;
    const int* edst = edge + N_EDGES;

    char* ws = (char*)d_ws;
    size_t off = 0;
    float* gpart = (float*)(ws + off); off += (size_t)2 * NGBLK * 4 + 252; off &= ~(size_t)255;
    float* A = (float*)(ws + off); off += (size_t)N_NODES * 128 * 4;
    float* B = (float*)(ws + off); off += (size_t)N_NODES * 128 * 4;
    int* rowptr = (int*)(ws + off); off += (size_t)(N_NODES + 1) * 4 + 252; off &= ~(size_t)255;
    int* cnt = (int*)(ws + off); off += (size_t)N_NODES * 4 + 252; off &= ~(size_t)255;
    int* cursor = (int*)(ws + off); off += (size_t)N_NODES * 4 + 252; off &= ~(size_t)255;
    int* csr_src = (int*)(ws + off); off += (size_t)N_EDGES * 4;
    int* elist = (int*)(ws + off); off += (size_t)N_NODES * 4 + 252; off &= ~(size_t)255;
    int* meta = (int*)(ws + off); off += 256;
    int* ecnt = meta;          // 16
    int* eoff = meta + 16;     // 17
    int* ecur = meta + 33;     // 16
    int* eidx = cnt;           // cnt is free after scan_kernel

    // ---- CSR build ----
    hipMemsetAsync(cnt, 0, (size_t)N_NODES * 4, stream);
    hist_kernel<<<(N_EDGES + 255) / 256, 256, 0, stream>>>(edst, cnt);
    scan_kernel<<<1, 1024, 0, stream>>>(cnt, rowptr, cursor);
    fill_kernel<<<(N_EDGES + 255) / 256, 256, 0, stream>>>(esrc, edst, cursor, csr_src);

    const int nbk = (N_NODES + 255) / 256;

    // ---- layer 1 ----
    gate_kernel<<<NGBLK, 256, 0, stream>>>(x, Wg1, bg1, eidx, gpart);
    hipMemsetAsync(ecnt, 0, 64, stream);
    hist16_kernel<<<nbk, 256, 0, stream>>>(eidx, ecnt);
    scan16_kernel<<<1, 64, 0, stream>>>(ecnt, eoff, ecur);
    scatter16_kernel<<<nbk, 256, 0, stream>>>(eidx, ecur, elist);
    expert_gemm_kernel<<<dim3(N_EXPERT, NYB), 256, 0, stream>>>(x, We1, be1, eoff, elist, A);
    gather_kernel<128, true><<<N_NODES, 128, 0, stream>>>(A, rowptr, csr_src, b1, B);

    // ---- layer 2 ----
    gate_kernel<<<NGBLK, 256, 0, stream>>>(B, Wg2, bg2, eidx, gpart + NGBLK);
    hipMemsetAsync(ecnt, 0, 64, stream);
    hist16_kernel<<<nbk, 256, 0, stream>>>(eidx, ecnt);
    scan16_kernel<<<1, 64, 0, stream>>>(ecnt, eoff, ecur);
    scatter16_kernel<<<nbk, 256, 0, stream>>>(eidx, ecur, elist);
    expert_gemm_kernel<<<dim3(N_EXPERT, NYB), 256, 0, stream>>>(B, We2, be2, eoff, elist, A);
    gather_kernel<128, true><<<N_NODES, 128, 0, stream>>>(A, rowptr, csr_src, b2, B);

    // ---- layer 3 (plain GCNConv) ----
    last_kernel<<<N_NODES / NB, 64, 0, stream>>>(B, Wlast, A);
    gather_kernel<64, false><<<N_NODES, 64, 0, stream>>>(A, rowptr, csr_src, blast, out);

    finalize_kernel<<<1, 1024, 0, stream>>>(gpart, out + (size_t)N_NODES * 64);
}